// Round 1
// baseline (70.771 us; speedup 1.0000x reference)
//
#include <hip/hip_runtime.h>
#include <hip/hip_bf16.h>

typedef int int4v  __attribute__((ext_vector_type(4)));
typedef int i32x16 __attribute__((ext_vector_type(16)));

#define ND 128
#define LD 128
#define EE 128
#define NQ 128
#define LQ 32

__device__ __forceinline__ unsigned q8u(float x) {
  float v = __builtin_rintf(x * 127.0f);          // inputs are L2-normalized: |x|<=1
  v = fminf(127.0f, fmaxf(-127.0f, v));
  return ((int)v) & 0xff;
}
__device__ __forceinline__ int imax(int a, int b) { return a > b ? a : b; }

// ---- Kernel 1 (R14): fp32 -> fragment-ordered i8, fixed scale 127.
// Doc path: 4 blocks per doc, DIRECT global->reg->global gather. The A-frag
// chunk ((d*4+mt)*4+ks)*64+lane wants i8(doc[d][mt*32+(lane&31)][ks*32+
// (lane>>5)*16 + 0..15]) -- those 16 e-values are 64 contiguous bytes of the
// fp32 source, so each thread reads 4 float4s and writes one uint4. No LDS,
// no barrier; every 64B line fully consumed (wave covers 128B/token).
// Query path unchanged (blocks [512,640)): LDS-transposed B-frags.
__global__ __launch_bounds__(256)
void convert_kernel(const float* __restrict__ doc, const float* __restrict__ qry,
                    unsigned char* __restrict__ docA8, unsigned char* __restrict__ qB8) {
  const int tid = threadIdx.x;
  const int b   = blockIdx.x;
  if (b < 512) {
    const int d  = b >> 2;
    const int mt = b & 3;
    const int ks = tid >> 6;                 // wave id
    const int lo = tid & 63;                 // lane
    const int t  = mt * 32 + (lo & 31);
    const int e0 = ks * 32 + (lo >> 5) * 16;
    const float4* src = reinterpret_cast<const float4*>(doc + d * LD * EE + t * EE + e0);
    unsigned w[4];
    #pragma unroll
    for (int dw = 0; dw < 4; ++dw) {
      float4 v = src[dw];
      w[dw] = q8u(v.x) | (q8u(v.y) << 8) | (q8u(v.z) << 16) | (q8u(v.w) << 24);
    }
    uint4 o; o.x = w[0]; o.y = w[1]; o.z = w[2]; o.w = w[3];
    const int cc = mt * 256 + tid;           // = (mt*4+ks)*64+lo; coalesced store
    reinterpret_cast<uint4*>(docA8 + d * 16384)[cc] = o;
    return;
  }
  const int q = b - 512;
  __shared__ float sq[EE * (LQ + 1)];        // 16.9 KB, pad 33 breaks banks
  const float* src = qry + q * EE * LQ;
  #pragma unroll
  for (int i = 0; i < 4; ++i) {              // 1024 float4 of [E][L], coalesced
    int c = i * 256 + tid;
    int e = c >> 3;
    int l = (c & 7) << 2;
    float4 v = reinterpret_cast<const float4*>(src)[c];
    sq[e * 33 + l + 0] = v.x;
    sq[e * 33 + l + 1] = v.y;
    sq[e * 33 + l + 2] = v.z;
    sq[e * 33 + l + 3] = v.w;
  }
  __syncthreads();
  uint4* dst = reinterpret_cast<uint4*>(qB8 + q * 4096);
  {
    int cc = tid;                            // exactly 256 chunks
    int ks = cc >> 6;
    int lo = cc & 63;
    int l  = lo & 31;
    int e0 = ks * 32 + (lo >> 5) * 16;
    unsigned w[4];
    #pragma unroll
    for (int dw = 0; dw < 4; ++dw)
      w[dw] = q8u(sq[(e0 + dw * 4 + 0) * 33 + l])
            | (q8u(sq[(e0 + dw * 4 + 1) * 33 + l]) << 8)
            | (q8u(sq[(e0 + dw * 4 + 2) * 33 + l]) << 16)
            | (q8u(sq[(e0 + dw * 4 + 3) * 33 + l]) << 24);
    uint4 o; o.x = w[0]; o.y = w[1]; o.z = w[2]; o.w = w[3];
    dst[cc] = o;
  }
}

// ---- Kernel 2 (R14): maxsim i8, full doc per wave, zero LDS, zero barriers.
// Changes vs R13: (1) p-loop FULLY unrolled -- loop body has no stores and no
// cross-lane ops, so the scheduler is free to hoist pass p+1's B-loads over
// pass p's MFMAs; the 128-MFMA stream issues near-continuously. (2) The
// shuffle reduction is DEFERRED: per-pass column maxes land in cm[8]
// (static indices only -- runtime-indexed ext_vector arrays go to scratch),
// and ONE batched reduce at the end runs all 8 queries' trees with 8-wide
// ILP per shfl level, replacing 4 serial ~12-deep ds_bpermute chains.
// Math (quantize, int max, scale, fp32 sum tree order) is bit-identical
// to R13. Regs ~190 est. (A 64 + B~2x32 + acc 32 + cm 8): 2 waves/SIMD ok,
// occupancy is grid-limited at 2 blocks/CU anyway. Grid (128 d, 4 qg).
__global__ __launch_bounds__(256)
void maxsim_kernel(const unsigned char* __restrict__ docA8,
                   const unsigned char* __restrict__ qB8,
                   float* __restrict__ out) {
  const int d    = blockIdx.x;
  const int qg   = blockIdx.y;
  const int tid  = threadIdx.x;
  const int wave = tid >> 6;
  const int lane = tid & 63;
  const int q0   = qg * 32 + wave * 8;     // this wave's 8 queries

  // A-frags: whole doc, 16 coalesced b128 loads (64 VGPRs), held permanently.
  const int4v* As = reinterpret_cast<const int4v*>(docA8) + d * 1024 + lane;
  int4v afrag[4][4];
  #pragma unroll
  for (int mt = 0; mt < 4; ++mt)
    #pragma unroll
    for (int ks = 0; ks < 4; ++ks)
      afrag[mt][ks] = As[(mt * 4 + ks) * 64];

  const int4v* Bs = reinterpret_cast<const int4v*>(qB8) + q0 * 256 + lane;

  int cm[8];                                // per-(pass,query) column maxes
  #pragma unroll
  for (int p = 0; p < 4; ++p) {
    // B-frags for this query pair: 8 coalesced b128 loads (32 VGPRs).
    const int4v* Bp = Bs + p * 512;
    int4v b0[4], b1[4];
    #pragma unroll
    for (int ks = 0; ks < 4; ++ks) {
      b0[ks] = Bp[ks * 64];
      b1[ks] = Bp[256 + ks * 64];
    }

    int cm0 = (int)0x80000000, cm1 = (int)0x80000000;
    #pragma unroll
    for (int mt = 0; mt < 4; ++mt) {
      i32x16 acc0 = {0, 0, 0, 0, 0, 0, 0, 0, 0, 0, 0, 0, 0, 0, 0, 0};
      i32x16 acc1 = acc0;
      #pragma unroll
      for (int ks = 0; ks < 4; ++ks) {     // 2 interleaved dep chains
        acc0 = __builtin_amdgcn_mfma_i32_32x32x32_i8(afrag[mt][ks], b0[ks], acc0, 0, 0, 0);
        acc1 = __builtin_amdgcn_mfma_i32_32x32x32_i8(afrag[mt][ks], b1[ks], acc1, 0, 0, 0);
      }
      // Fold 16 acc rows into the running per-column maxes (VALU pipe,
      // overlaps the next mt's MFMAs).
      int m0 = imax(imax(imax(imax(acc0[0], acc0[1]),  imax(acc0[2], acc0[3])),
                         imax(imax(acc0[4], acc0[5]),  imax(acc0[6], acc0[7]))),
                    imax(imax(imax(acc0[8], acc0[9]),  imax(acc0[10], acc0[11])),
                         imax(imax(acc0[12], acc0[13]), imax(acc0[14], acc0[15]))));
      cm0 = imax(cm0, m0);
      int m1 = imax(imax(imax(imax(acc1[0], acc1[1]),  imax(acc1[2], acc1[3])),
                         imax(imax(acc1[4], acc1[5]),  imax(acc1[6], acc1[7]))),
                    imax(imax(imax(acc1[8], acc1[9]),  imax(acc1[10], acc1[11])),
                         imax(imax(acc1[12], acc1[13]), imax(acc1[14], acc1[15]))));
      cm1 = imax(cm1, m1);
    }
    cm[2 * p]     = cm0;                   // static indices (p fully unrolled)
    cm[2 * p + 1] = cm1;
  }

  // Deferred reduction: xor32 merges kh halves -> max over all 128 doc
  // tokens for col lane&31; scale once; 5-level xor sum tree, 8-wide ILP.
  float f[8];
  #pragma unroll
  for (int i = 0; i < 8; ++i) {
    int c = imax(cm[i], __shfl_xor(cm[i], 32, 64));
    f[i] = (float)c * (1.0f / 16129.0f);
  }
  #pragma unroll
  for (int s = 1; s <= 16; s <<= 1) {
    #pragma unroll
    for (int i = 0; i < 8; ++i)
      f[i] += __shfl_xor(f[i], s, 64);
  }
  if (lane == 0) {
    #pragma unroll
    for (int i = 0; i < 8; ++i)
      out[(q0 + i) * ND + d] = f[i];
  }
}

extern "C" void kernel_launch(void* const* d_in, const int* in_sizes, int n_in,
                              void* d_out, int out_size, void* d_ws, size_t ws_size,
                              hipStream_t stream) {
  const float* doc = (const float*)d_in[0];   // [128,128,128] fp32
  const float* qry = (const float*)d_in[1];   // [128,128,32]  fp32
  float* out = (float*)d_out;                 // [128,128]     fp32

  unsigned char* docA8 = (unsigned char*)d_ws;             // 2 MiB, frag-ordered i8
  unsigned char* qB8   = docA8 + ND * LD * EE;             // 512 KiB, frag-ordered i8

  convert_kernel<<<dim3(640), dim3(256), 0, stream>>>(doc, qry, docA8, qB8);
  maxsim_kernel<<<dim3(ND, NQ / 32), dim3(256), 0, stream>>>(docA8, qB8, out);
}